// Round 1
// baseline (445.629 us; speedup 1.0000x reference)
//
#include <hip/hip_runtime.h>
#include <hip/hip_bf16.h>
#include <cstdint>

typedef __bf16 bf16x8 __attribute__((ext_vector_type(8)));
typedef float floatx4 __attribute__((ext_vector_type(4)));

__device__ __forceinline__ void gl2lds16(const void* g, void* l) {
  __builtin_amdgcn_global_load_lds(
      (const __attribute__((address_space(1))) unsigned int*)g,
      (__attribute__((address_space(3))) unsigned int*)(uintptr_t)l,
      16, 0, 0);
}

// ---------------- fp32 -> bf16 convert ----------------
__global__ __launch_bounds__(256)
void cvt_kernel(const float* __restrict__ in, __hip_bfloat16* __restrict__ out, int n) {
  int i = (blockIdx.x * 256 + threadIdx.x) * 4;
  if (i >= n) return;
  const float4 v = *(const float4*)(in + i);
  out[i + 0] = __float2bfloat16(v.x);
  out[i + 1] = __float2bfloat16(v.y);
  out[i + 2] = __float2bfloat16(v.z);
  out[i + 3] = __float2bfloat16(v.w);
}

// ---------------- bf16 GEMM: C[M][Nc] = A[M][K] * B[Nc][K]^T ----------------
// 128x128 tile, BK=32, 256 threads (4 waves in 2x2), m97 structure.
__global__ __launch_bounds__(256)
void gemm_bt(const __hip_bfloat16* __restrict__ A, const __hip_bfloat16* __restrict__ Bm,
             void* __restrict__ Cp, int M, int Nc, int K, int c_fp32)
{
  __shared__ __hip_bfloat16 As[128 * 32];
  __shared__ __hip_bfloat16 Bs[128 * 32];
  const int tid = threadIdx.x;
  const int lane = tid & 63, wave = tid >> 6;
  const int wm = (wave & 1) * 64, wn = (wave >> 1) * 64;
  const int m0 = blockIdx.x * 128, n0 = blockIdx.y * 128;
  const int lrow = lane & 15, lk = (lane >> 4) * 8;
  floatx4 acc[4][4] = {};
  const int c0 = tid, c1 = tid + 256;
  const int r0 = c0 >> 2, o0 = (c0 & 3) * 8;
  const int r1 = c1 >> 2, o1 = (c1 & 3) * 8;
  for (int kt = 0; kt < K; kt += 32) {
    __syncthreads();
    gl2lds16(A + (size_t)(m0 + r0) * K + kt + o0, &As[c0 * 8]);
    gl2lds16(A + (size_t)(m0 + r1) * K + kt + o1, &As[c1 * 8]);
    gl2lds16(Bm + (size_t)(n0 + r0) * K + kt + o0, &Bs[c0 * 8]);
    gl2lds16(Bm + (size_t)(n0 + r1) * K + kt + o1, &Bs[c1 * 8]);
    __syncthreads();
    bf16x8 af[4], bfr[4];
#pragma unroll
    for (int t = 0; t < 4; t++) af[t] = *(const bf16x8*)&As[(wm + t * 16 + lrow) * 32 + lk];
#pragma unroll
    for (int t = 0; t < 4; t++) bfr[t] = *(const bf16x8*)&Bs[(wn + t * 16 + lrow) * 32 + lk];
#pragma unroll
    for (int mt = 0; mt < 4; mt++)
#pragma unroll
      for (int nt = 0; nt < 4; nt++)
        acc[mt][nt] = __builtin_amdgcn_mfma_f32_16x16x32_bf16(af[mt], bfr[nt], acc[mt][nt], 0, 0, 0);
  }
  const int lq4 = (lane >> 4) * 4;
#pragma unroll
  for (int mt = 0; mt < 4; mt++)
#pragma unroll
    for (int nt = 0; nt < 4; nt++)
#pragma unroll
      for (int r = 0; r < 4; r++) {
        const int m = m0 + wm + mt * 16 + lq4 + r;
        const int n = n0 + wn + nt * 16 + lrow;
        const float v = acc[mt][nt][r];
        if (c_fp32) ((float*)Cp)[(size_t)m * Nc + n] = v;
        else ((__hip_bfloat16*)Cp)[(size_t)m * Nc + n] = __float2bfloat16(v);
      }
}

// ---------------- RoPE + relayout ----------------
// qkv: [B*N][6144] bf16.  Out: Qr,Kr [B*H][N][128], Vt [B*H][128][N] (transposed).
__global__ __launch_bounds__(256)
void rope_relayout(const __hip_bfloat16* __restrict__ qkv,
                   __hip_bfloat16* __restrict__ Qr, __hip_bfloat16* __restrict__ Kr,
                   __hip_bfloat16* __restrict__ Vt)
{
  const int nt = blockIdx.x, bh = blockIdx.y;
  const int b = bh >> 4, h = bh & 15;
  const int n0 = nt * 64;
  const int tid = threadIdx.x;
  const int d = tid & 127, rr = tid >> 7;
  const int half = d & 63;
  // inv_freq = 10000^(-half/64) = exp(-half * ln(10000)/64)
  const float inv_freq = __expf(-(float)half * 0.14391156831212787f);
  __shared__ __hip_bfloat16 vtile[128][72];  // pad to 72 (row=144B, 16B aligned)
  for (int nn = rr; nn < 64; nn += 2) {
    const int n = n0 + nn;
    const size_t base = ((size_t)(b * 2048 + n)) * 6144 + h * 128;
    const float qv = __bfloat162float(qkv[base + d]);
    const float qp = __bfloat162float(qkv[base + (d ^ 64)]);
    const float kv = __bfloat162float(qkv[base + 2048 + d]);
    const float kp = __bfloat162float(qkv[base + 2048 + (d ^ 64)]);
    const float ang = (float)n * inv_freq;
    float sn, cs;
    __sincosf(ang, &sn, &cs);
    const float rotq = (d < 64) ? -qp : qp;
    const float rotk = (d < 64) ? -kp : kp;
    const size_t ob = ((size_t)bh * 2048 + n) * 128 + d;
    Qr[ob] = __float2bfloat16(qv * cs + rotq * sn);
    Kr[ob] = __float2bfloat16(kv * cs + rotk * sn);
    vtile[d][nn] = qkv[base + 4096 + d];
  }
  __syncthreads();
  const int dv = tid >> 1, cb = (tid & 1) * 32;
  const size_t vb = ((size_t)bh * 128 + dv) * 2048 + n0 + cb;
#pragma unroll
  for (int jj = 0; jj < 32; jj++) Vt[vb + jj] = vtile[dv][cb + jj];
}

// ---------------- sliding-window flash attention ----------------
// grid (32 qtiles, 32 bh). 64 q-rows per block, 16 per wave. 64-key tiles.
__global__ __launch_bounds__(256)
void attn_swa(const __hip_bfloat16* __restrict__ Qr, const __hip_bfloat16* __restrict__ Kr,
              const __hip_bfloat16* __restrict__ Vt, __hip_bfloat16* __restrict__ Out)
{
  __shared__ __hip_bfloat16 Qs[64 * 128];
  __shared__ __hip_bfloat16 Ks[64 * 128];
  __shared__ __hip_bfloat16 Vs[128 * 64];   // V^T tile: [d][j]
  __shared__ __hip_bfloat16 Pb[4][16 * 64]; // per-wave P transpose buffer
  const int qt = blockIdx.x, bh = blockIdx.y;
  const int tid = threadIdx.x, lane = tid & 63, wave = tid >> 6;
  const int lrow = lane & 15, lk = (lane >> 4) * 8, lq4 = (lane >> 4) * 4;
  const int i0 = qt * 64;
  const float NEG_INF = -__builtin_inff();
  const __hip_bfloat16* Qh = Qr + (size_t)bh * 2048 * 128;
  const __hip_bfloat16* Kh = Kr + (size_t)bh * 2048 * 128;
  const __hip_bfloat16* Vh = Vt + (size_t)bh * 128 * 2048;
#pragma unroll
  for (int it = 0; it < 4; it++) {
    const int c = it * 256 + tid;
    gl2lds16(Qh + (size_t)(i0 + (c >> 4)) * 128 + (c & 15) * 8, &Qs[c * 8]);
  }
  floatx4 accO[8] = {};
  float m_i[4], l_i[4];
#pragma unroll
  for (int r = 0; r < 4; r++) { m_i[r] = NEG_INF; l_i[r] = 0.f; }
  const int lo = i0 - 511;
  const int jt_lo = (lo > 0 ? lo : 0) >> 6;
  const int jt_hi = i0 >> 6;
  for (int jt = jt_lo; jt <= jt_hi; jt++) {
    const int j0 = jt * 64;
    __syncthreads();  // drains prior-iter LDS reads (and initial Q staging vmcnt)
#pragma unroll
    for (int it = 0; it < 4; it++) {
      const int c = it * 256 + tid;
      gl2lds16(Kh + (size_t)(j0 + (c >> 4)) * 128 + (c & 15) * 8, &Ks[c * 8]);
      gl2lds16(Vh + (size_t)(c >> 3) * 2048 + j0 + (c & 7) * 8, &Vs[c * 8]);
    }
    __syncthreads();
    // S[16q x 64j] = Q K^T
    bf16x8 aq[4];
#pragma unroll
    for (int ks = 0; ks < 4; ks++)
      aq[ks] = *(const bf16x8*)&Qs[(wave * 16 + lrow) * 128 + ks * 32 + lk];
    floatx4 s[4] = {};
#pragma unroll
    for (int nt = 0; nt < 4; nt++)
#pragma unroll
      for (int ks = 0; ks < 4; ks++) {
        const bf16x8 bk = *(const bf16x8*)&Ks[(nt * 16 + lrow) * 128 + ks * 32 + lk];
        s[nt] = __builtin_amdgcn_mfma_f32_16x16x32_bf16(aq[ks], bk, s[nt], 0, 0, 0);
      }
    // mask + scale; row max
    float rmax[4];
#pragma unroll
    for (int r = 0; r < 4; r++) rmax[r] = NEG_INF;
#pragma unroll
    for (int nt = 0; nt < 4; nt++) {
      const int j = j0 + nt * 16 + lrow;
#pragma unroll
      for (int r = 0; r < 4; r++) {
        const int i = i0 + wave * 16 + lq4 + r;
        float sv = s[nt][r] * 0.08838834764831845f;  // 1/sqrt(128)
        sv = ((j <= i) && (j > i - 512)) ? sv : NEG_INF;
        s[nt][r] = sv;
        rmax[r] = fmaxf(rmax[r], sv);
      }
    }
#pragma unroll
    for (int off = 1; off < 16; off <<= 1)
#pragma unroll
      for (int r = 0; r < 4; r++)
        rmax[r] = fmaxf(rmax[r], __shfl_xor(rmax[r], off, 16));
    float alpha[4], mnew[4];
#pragma unroll
    for (int r = 0; r < 4; r++) {
      mnew[r] = fmaxf(m_i[r], rmax[r]);
      // fminf(nan,0)=0 handles (-inf)-(-inf); exp(-inf)=0 handles fresh-row case
      alpha[r] = __expf(fminf(m_i[r] - mnew[r], 0.f));
      m_i[r] = mnew[r];
    }
    float rs[4] = {0.f, 0.f, 0.f, 0.f};
#pragma unroll
    for (int nt = 0; nt < 4; nt++)
#pragma unroll
      for (int r = 0; r < 4; r++) {
        const float sv = s[nt][r];
        const float p = (sv == NEG_INF) ? 0.f : __expf(sv - mnew[r]);
        s[nt][r] = p;
        rs[r] += p;
      }
#pragma unroll
    for (int off = 1; off < 16; off <<= 1)
#pragma unroll
      for (int r = 0; r < 4; r++) rs[r] += __shfl_xor(rs[r], off, 16);
    floatx4 av;
#pragma unroll
    for (int r = 0; r < 4; r++) { l_i[r] = l_i[r] * alpha[r] + rs[r]; av[r] = alpha[r]; }
#pragma unroll
    for (int dt = 0; dt < 8; dt++) accO[dt] *= av;
    // P: C-layout -> LDS -> A-layout
#pragma unroll
    for (int nt = 0; nt < 4; nt++)
#pragma unroll
      for (int r = 0; r < 4; r++)
        Pb[wave][(lq4 + r) * 64 + nt * 16 + lrow] = __float2bfloat16(s[nt][r]);
    __syncthreads();
    bf16x8 pa[2];
#pragma unroll
    for (int jf = 0; jf < 2; jf++)
      pa[jf] = *(const bf16x8*)&Pb[wave][lrow * 64 + jf * 32 + lk];
#pragma unroll
    for (int dt = 0; dt < 8; dt++)
#pragma unroll
      for (int jf = 0; jf < 2; jf++) {
        const bf16x8 bv = *(const bf16x8*)&Vs[(dt * 16 + lrow) * 64 + jf * 32 + lk];
        accO[dt] = __builtin_amdgcn_mfma_f32_16x16x32_bf16(pa[jf], bv, accO[dt], 0, 0, 0);
      }
  }
  const int b = bh >> 4, h = bh & 15;
#pragma unroll
  for (int dt = 0; dt < 8; dt++)
#pragma unroll
    for (int r = 0; r < 4; r++) {
      const int i = i0 + wave * 16 + lq4 + r;
      const int d = dt * 16 + lrow;
      Out[((size_t)(b * 2048 + i)) * 2048 + h * 128 + d] =
          __float2bfloat16(accO[dt][r] / l_i[r]);
    }
}

// ---------------- launch ----------------
extern "C" void kernel_launch(void* const* d_in, const int* in_sizes, int n_in,
                              void* d_out, int out_size, void* d_ws, size_t ws_size,
                              hipStream_t stream)
{
  const float* x = (const float*)d_in[0];      // [2,2048,2048]
  const float* w_qkv = (const float*)d_in[1];  // [6144,2048]
  const float* w_o = (const float*)d_in[2];    // [2048,2048]
  float* y = (float*)d_out;                    // [2,2048,2048] fp32
  char* ws = (char*)d_ws;

  const size_t SZ_X = 16777216;     // 4096*2048*2
  const size_t SZ_WQKV = 25165824;  // 6144*2048*2
  const size_t SZ_QKV = 50331648;   // 4096*6144*2
  const size_t SZ_HD = 16777216;    // 32*2048*128*2

  __hip_bfloat16* xb = (__hip_bfloat16*)(ws);                          // also attn_out later
  __hip_bfloat16* wqkvb = (__hip_bfloat16*)(ws + SZ_X);                // also w_o bf16 later
  __hip_bfloat16* qkv = (__hip_bfloat16*)(ws + SZ_X + SZ_WQKV);
  __hip_bfloat16* Qr = (__hip_bfloat16*)(ws + SZ_X + SZ_WQKV + SZ_QKV);
  __hip_bfloat16* Kr = Qr + SZ_HD / 2;
  __hip_bfloat16* Vt = Kr + SZ_HD / 2;

  cvt_kernel<<<dim3(8192), dim3(256), 0, stream>>>(x, xb, 8388608);
  cvt_kernel<<<dim3(12288), dim3(256), 0, stream>>>(w_qkv, wqkvb, 12582912);
  gemm_bt<<<dim3(32, 48), dim3(256), 0, stream>>>(xb, wqkvb, (void*)qkv, 4096, 6144, 2048, 0);
  rope_relayout<<<dim3(32, 32), dim3(256), 0, stream>>>(qkv, Qr, Kr, Vt);
  attn_swa<<<dim3(32, 32), dim3(256), 0, stream>>>(Qr, Kr, Vt, xb /*attn_out*/);
  cvt_kernel<<<dim3(4096), dim3(256), 0, stream>>>(w_o, wqkvb, 4194304);
  gemm_bt<<<dim3(32, 16), dim3(256), 0, stream>>>(xb, wqkvb, (void*)y, 4096, 2048, 2048, 1);
}

// Round 2
// 413.540 us; speedup vs baseline: 1.0776x; 1.0776x over previous
//
#include <hip/hip_runtime.h>
#include <hip/hip_bf16.h>
#include <cstdint>

typedef __bf16 bf16x8 __attribute__((ext_vector_type(8)));
typedef float floatx4 __attribute__((ext_vector_type(4)));

__device__ __forceinline__ void gl2lds16(const void* g, void* l) {
  __builtin_amdgcn_global_load_lds(
      (const __attribute__((address_space(1))) unsigned int*)g,
      (__attribute__((address_space(3))) unsigned int*)(uintptr_t)l,
      16, 0, 0);
}

// ---------------- fp32 -> bf16 convert ----------------
__global__ __launch_bounds__(256)
void cvt_kernel(const float* __restrict__ in, __hip_bfloat16* __restrict__ out, int n) {
  int i = (blockIdx.x * 256 + threadIdx.x) * 4;
  if (i >= n) return;
  const float4 v = *(const float4*)(in + i);
  out[i + 0] = __float2bfloat16(v.x);
  out[i + 1] = __float2bfloat16(v.y);
  out[i + 2] = __float2bfloat16(v.z);
  out[i + 3] = __float2bfloat16(v.w);
}

// ---------------- plain bf16 GEMM (O-proj): C[M][Nc] = A[M][K] * B[Nc][K]^T ----
__global__ __launch_bounds__(256)
void gemm_bt(const __hip_bfloat16* __restrict__ A, const __hip_bfloat16* __restrict__ Bm,
             void* __restrict__ Cp, int M, int Nc, int K, int c_fp32)
{
  __shared__ __hip_bfloat16 As[128 * 32];
  __shared__ __hip_bfloat16 Bs[128 * 32];
  const int tid = threadIdx.x;
  const int lane = tid & 63, wave = tid >> 6;
  const int wm = (wave & 1) * 64, wn = (wave >> 1) * 64;
  const int m0 = blockIdx.x * 128, n0 = blockIdx.y * 128;
  const int lrow = lane & 15, lk = (lane >> 4) * 8;
  floatx4 acc[4][4] = {};
  const int c0 = tid, c1 = tid + 256;
  const int r0 = c0 >> 2, o0 = (c0 & 3) * 8;
  const int r1 = c1 >> 2, o1 = (c1 & 3) * 8;
  for (int kt = 0; kt < K; kt += 32) {
    __syncthreads();
    gl2lds16(A + (size_t)(m0 + r0) * K + kt + o0, &As[c0 * 8]);
    gl2lds16(A + (size_t)(m0 + r1) * K + kt + o1, &As[c1 * 8]);
    gl2lds16(Bm + (size_t)(n0 + r0) * K + kt + o0, &Bs[c0 * 8]);
    gl2lds16(Bm + (size_t)(n0 + r1) * K + kt + o1, &Bs[c1 * 8]);
    __syncthreads();
    bf16x8 af[4], bfr[4];
#pragma unroll
    for (int t = 0; t < 4; t++) af[t] = *(const bf16x8*)&As[(wm + t * 16 + lrow) * 32 + lk];
#pragma unroll
    for (int t = 0; t < 4; t++) bfr[t] = *(const bf16x8*)&Bs[(wn + t * 16 + lrow) * 32 + lk];
#pragma unroll
    for (int mt = 0; mt < 4; mt++)
#pragma unroll
      for (int nt = 0; nt < 4; nt++)
        acc[mt][nt] = __builtin_amdgcn_mfma_f32_16x16x32_bf16(af[mt], bfr[nt], acc[mt][nt], 0, 0, 0);
  }
  const int lq4 = (lane >> 4) * 4;
#pragma unroll
  for (int mt = 0; mt < 4; mt++)
#pragma unroll
    for (int nt = 0; nt < 4; nt++)
#pragma unroll
      for (int r = 0; r < 4; r++) {
        const int m = m0 + wm + mt * 16 + lq4 + r;
        const int n = n0 + wn + nt * 16 + lrow;
        const float v = acc[mt][nt][r];
        if (c_fp32) ((float*)Cp)[(size_t)m * Nc + n] = v;
        else ((__hip_bfloat16*)Cp)[(size_t)m * Nc + n] = __float2bfloat16(v);
      }
}

// ---------------- QKV GEMM with fused RoPE + relayout epilogue ----------------
// A = x bf16 [4096][2048]; W = w_qkv bf16 [6144][2048].
// n0<2048: Q -> rope*scale -> Qr[bh][seq][128]
// n0<4096: K -> rope       -> Kr[bh][seq][128]
// else   : V -> transpose  -> Vt[bh][128][seq]
__global__ __launch_bounds__(256)
void gemm_qkv_fused(const __hip_bfloat16* __restrict__ A,
                    const __hip_bfloat16* __restrict__ W,
                    __hip_bfloat16* __restrict__ Qr,
                    __hip_bfloat16* __restrict__ Kr,
                    __hip_bfloat16* __restrict__ Vt)
{
  __shared__ alignas(16) char smem[16640];     // union: As+Bs (16384) | Cs 64x130 bf16 (16640)
  __shared__ float invf[64];
  __hip_bfloat16* As = (__hip_bfloat16*)smem;
  __hip_bfloat16* Bs = As + 128 * 32;
  __hip_bfloat16* Cs = (__hip_bfloat16*)smem;  // [64][130] (pad 130: stride 65 dwords == 1 mod 32)
  const int tid = threadIdx.x;
  if (tid < 64) invf[tid] = __expf(-(float)tid * 0.14391156831212787f);  // 10000^(-t/64)
  const int lane = tid & 63, wave = tid >> 6;
  const int wm = (wave & 1) * 64, wn = (wave >> 1) * 64;
  const int m0 = blockIdx.x * 128, n0 = blockIdx.y * 128;
  const int K = 2048;
  const int lrow = lane & 15, lk = (lane >> 4) * 8;
  floatx4 acc[4][4] = {};
  const int c0 = tid, c1 = tid + 256;
  const int r0 = c0 >> 2, o0 = (c0 & 3) * 8;
  const int r1 = c1 >> 2, o1 = (c1 & 3) * 8;
  for (int kt = 0; kt < K; kt += 32) {
    __syncthreads();
    gl2lds16(A + (size_t)(m0 + r0) * K + kt + o0, &As[c0 * 8]);
    gl2lds16(A + (size_t)(m0 + r1) * K + kt + o1, &As[c1 * 8]);
    gl2lds16(W + (size_t)(n0 + r0) * K + kt + o0, &Bs[c0 * 8]);
    gl2lds16(W + (size_t)(n0 + r1) * K + kt + o1, &Bs[c1 * 8]);
    __syncthreads();
    bf16x8 af[4], bfr[4];
#pragma unroll
    for (int t = 0; t < 4; t++) af[t] = *(const bf16x8*)&As[(wm + t * 16 + lrow) * 32 + lk];
#pragma unroll
    for (int t = 0; t < 4; t++) bfr[t] = *(const bf16x8*)&Bs[(wn + t * 16 + lrow) * 32 + lk];
#pragma unroll
    for (int mt = 0; mt < 4; mt++)
#pragma unroll
      for (int nt = 0; nt < 4; nt++)
        acc[mt][nt] = __builtin_amdgcn_mfma_f32_16x16x32_bf16(af[mt], bfr[nt], acc[mt][nt], 0, 0, 0);
  }
  const int lq4 = (lane >> 4) * 4;
  const int seg = n0 >> 11;            // 0=Q 1=K 2=V (tile never straddles: 128 | 2048)
  const int h = (n0 & 2047) >> 7;      // head (tile never straddles a head: 128-wide)
  const int b = m0 >> 11;
  const int bh = b * 16 + h;
  const int seq0 = m0 & 2047;
  const float qscale = (seg == 0) ? 0.08838834764831845f : 1.0f;  // 1/sqrt(128) folded into Q
  // two row-half passes so Cs fits in the staging LDS footprint
  for (int pass = 0; pass < 2; ++pass) {
    __syncthreads();                   // staging/MFMA LDS reads done; Cs reuse safe
    if ((wave & 1) == pass) {          // waves holding rows [pass*64, pass*64+64)
#pragma unroll
      for (int mt = 0; mt < 4; mt++)
#pragma unroll
        for (int nt = 0; nt < 4; nt++)
#pragma unroll
          for (int r = 0; r < 4; r++)
            Cs[(mt * 16 + lq4 + r) * 130 + wn + nt * 16 + lrow] =
                __float2bfloat16(acc[mt][nt][r]);
    }
    __syncthreads();
    if (seg < 2) {
      __hip_bfloat16* Out = seg ? Kr : Qr;
#pragma unroll
      for (int p = 0; p < 2; ++p) {
        const int row = (tid >> 3) + p * 32;       // local row 0..63
        const int oct = (tid & 7) * 8;             // d base in [0,64)
        const int m = m0 + pass * 64 + row;
        const float pos = (float)(m & 2047);
        alignas(16) __hip_bfloat16 lo[8], hi[8];
#pragma unroll
        for (int k2 = 0; k2 < 8; k2++) {
          const float ang = pos * invf[oct + k2];
          float sn, cs2;
          __sincosf(ang, &sn, &cs2);
          const float a  = __bfloat162float(Cs[row * 130 + oct + k2]);
          const float bb = __bfloat162float(Cs[row * 130 + oct + k2 + 64]);
          lo[k2] = __float2bfloat16((a * cs2 - bb * sn) * qscale);   // d<64: t1*cos - t2*sin
          hi[k2] = __float2bfloat16((bb * cs2 + a * sn) * qscale);   // d>=64: t2*cos + t1*sin
        }
        const size_t ob = ((size_t)bh * 2048 + (size_t)(m & 2047)) * 128;
        *(bf16x8*)&Out[ob + oct]      = *(const bf16x8*)lo;
        *(bf16x8*)&Out[ob + oct + 64] = *(const bf16x8*)hi;
      }
    } else {
      // V transpose: Vt[bh][d][seq]
#pragma unroll
      for (int p = 0; p < 4; ++p) {
        const int d = (tid >> 3) + p * 32;         // 0..127
        const int s8 = (tid & 7) * 8;              // seq offset within this 64-row pass
        alignas(16) __hip_bfloat16 tmp[8];
#pragma unroll
        for (int k2 = 0; k2 < 8; k2++) tmp[k2] = Cs[(s8 + k2) * 130 + d];
        const size_t ob = ((size_t)bh * 128 + d) * 2048 + seq0 + pass * 64 + s8;
        *(bf16x8*)&Vt[ob] = *(const bf16x8*)tmp;
      }
    }
  }
}

// ---------------- sliding-window flash attention ----------------
// Q pre-scaled by 1/sqrt(128). grid (32 qtiles, 32 bh).
__global__ __launch_bounds__(256)
void attn_swa(const __hip_bfloat16* __restrict__ Qr, const __hip_bfloat16* __restrict__ Kr,
              const __hip_bfloat16* __restrict__ Vt, __hip_bfloat16* __restrict__ Out)
{
  __shared__ __hip_bfloat16 Qs[64 * 128];
  __shared__ __hip_bfloat16 Ks[64 * 128];
  __shared__ __hip_bfloat16 Vs[128 * 64];   // V^T tile: [d][j]
  __shared__ __hip_bfloat16 Pb[4][16 * 64]; // per-wave (wave-private: no barrier needed)
  const int qt = blockIdx.x, bh = blockIdx.y;
  const int tid = threadIdx.x, lane = tid & 63, wave = tid >> 6;
  const int lrow = lane & 15, lk = (lane >> 4) * 8, lq4 = (lane >> 4) * 4;
  const int i0 = qt * 64;
  const float NEG_INF = -__builtin_inff();
  const __hip_bfloat16* Qh = Qr + (size_t)bh * 2048 * 128;
  const __hip_bfloat16* Kh = Kr + (size_t)bh * 2048 * 128;
  const __hip_bfloat16* Vh = Vt + (size_t)bh * 128 * 2048;
#pragma unroll
  for (int it = 0; it < 4; it++) {
    const int c = it * 256 + tid;
    gl2lds16(Qh + (size_t)(i0 + (c >> 4)) * 128 + (c & 15) * 8, &Qs[c * 8]);
  }
  floatx4 accO[8] = {};
  float m_i[4], l_i[4];
#pragma unroll
  for (int r = 0; r < 4; r++) { m_i[r] = NEG_INF; l_i[r] = 0.f; }
  const int lo = i0 - 511;
  const int jt_lo = (lo > 0 ? lo : 0) >> 6;
  const int jt_hi = i0 >> 6;
  const int imin = i0 + wave * 16;
  bf16x8 aq[4];
  for (int jt = jt_lo; jt <= jt_hi; jt++) {
    const int j0 = jt * 64;
    __syncthreads();  // prior-iter LDS reads done (and drains initial Q staging vmcnt)
#pragma unroll
    for (int it = 0; it < 4; it++) {
      const int c = it * 256 + tid;
      gl2lds16(Kh + (size_t)(j0 + (c >> 4)) * 128 + (c & 15) * 8, &Ks[c * 8]);
      gl2lds16(Vh + (size_t)(c >> 3) * 2048 + j0 + (c & 7) * 8, &Vs[c * 8]);
    }
    __syncthreads();
    if (jt == jt_lo) {  // hoisted Q fragment read (wave-uniform branch)
#pragma unroll
      for (int ks = 0; ks < 4; ks++)
        aq[ks] = *(const bf16x8*)&Qs[(wave * 16 + lrow) * 128 + ks * 32 + lk];
    }
    // S[16q x 64j] = Q K^T (Q pre-scaled)
    floatx4 s[4] = {};
#pragma unroll
    for (int nt = 0; nt < 4; nt++)
#pragma unroll
      for (int ks = 0; ks < 4; ks++) {
        const bf16x8 bk = *(const bf16x8*)&Ks[(nt * 16 + lrow) * 128 + ks * 32 + lk];
        s[nt] = __builtin_amdgcn_mfma_f32_16x16x32_bf16(aq[ks], bk, s[nt], 0, 0, 0);
      }
    // interior tiles (fully inside the window for this wave's 16 rows): no masking
    const bool full = (j0 + 63 <= imin) && (j0 >= imin + 15 - 511);
    float rmax[4];
#pragma unroll
    for (int r = 0; r < 4; r++) rmax[r] = NEG_INF;
    if (full) {
#pragma unroll
      for (int nt = 0; nt < 4; nt++)
#pragma unroll
        for (int r = 0; r < 4; r++) rmax[r] = fmaxf(rmax[r], s[nt][r]);
    } else {
#pragma unroll
      for (int nt = 0; nt < 4; nt++) {
        const int j = j0 + nt * 16 + lrow;
#pragma unroll
        for (int r = 0; r < 4; r++) {
          const int i = i0 + wave * 16 + lq4 + r;
          const float sv = ((j <= i) && (j > i - 512)) ? s[nt][r] : NEG_INF;
          s[nt][r] = sv;
          rmax[r] = fmaxf(rmax[r], sv);
        }
      }
    }
#pragma unroll
    for (int off = 1; off < 16; off <<= 1)
#pragma unroll
      for (int r = 0; r < 4; r++)
        rmax[r] = fmaxf(rmax[r], __shfl_xor(rmax[r], off, 16));
    float alpha[4], mnew[4];
#pragma unroll
    for (int r = 0; r < 4; r++) {
      mnew[r] = fmaxf(m_i[r], rmax[r]);
      alpha[r] = __expf(fminf(m_i[r] - mnew[r], 0.f));  // guards (-inf)-(-inf)
      m_i[r] = mnew[r];
    }
    float rs[4] = {0.f, 0.f, 0.f, 0.f};
    if (full) {
#pragma unroll
      for (int nt = 0; nt < 4; nt++)
#pragma unroll
        for (int r = 0; r < 4; r++) {
          const float p = __expf(s[nt][r] - mnew[r]);
          s[nt][r] = p;
          rs[r] += p;
        }
    } else {
#pragma unroll
      for (int nt = 0; nt < 4; nt++)
#pragma unroll
        for (int r = 0; r < 4; r++) {
          const float sv = s[nt][r];
          const float p = (sv == NEG_INF) ? 0.f : __expf(sv - mnew[r]);
          s[nt][r] = p;
          rs[r] += p;
        }
    }
#pragma unroll
    for (int off = 1; off < 16; off <<= 1)
#pragma unroll
      for (int r = 0; r < 4; r++) rs[r] += __shfl_xor(rs[r], off, 16);
    floatx4 av;
#pragma unroll
    for (int r = 0; r < 4; r++) { l_i[r] = l_i[r] * alpha[r] + rs[r]; av[r] = alpha[r]; }
#pragma unroll
    for (int dt = 0; dt < 8; dt++) accO[dt] *= av;
    // P: C-layout -> wave-private LDS -> A-layout (no barrier: same-wave lgkmcnt suffices)
#pragma unroll
    for (int nt = 0; nt < 4; nt++)
#pragma unroll
      for (int r = 0; r < 4; r++)
        Pb[wave][(lq4 + r) * 64 + nt * 16 + lrow] = __float2bfloat16(s[nt][r]);
    bf16x8 pa[2];
#pragma unroll
    for (int jf = 0; jf < 2; jf++)
      pa[jf] = *(const bf16x8*)&Pb[wave][lrow * 64 + jf * 32 + lk];
#pragma unroll
    for (int dt = 0; dt < 8; dt++)
#pragma unroll
      for (int jf = 0; jf < 2; jf++) {
        const bf16x8 bv = *(const bf16x8*)&Vs[(dt * 16 + lrow) * 64 + jf * 32 + lk];
        accO[dt] = __builtin_amdgcn_mfma_f32_16x16x32_bf16(pa[jf], bv, accO[dt], 0, 0, 0);
      }
  }
  const int b = bh >> 4, h = bh & 15;
#pragma unroll
  for (int dt = 0; dt < 8; dt++)
#pragma unroll
    for (int r = 0; r < 4; r++) {
      const int i = i0 + wave * 16 + lq4 + r;
      const int d = dt * 16 + lrow;
      Out[((size_t)(b * 2048 + i)) * 2048 + h * 128 + d] =
          __float2bfloat16(accO[dt][r] / l_i[r]);
    }
}

// ---------------- launch ----------------
extern "C" void kernel_launch(void* const* d_in, const int* in_sizes, int n_in,
                              void* d_out, int out_size, void* d_ws, size_t ws_size,
                              hipStream_t stream)
{
  const float* x = (const float*)d_in[0];      // [2,2048,2048]
  const float* w_qkv = (const float*)d_in[1];  // [6144,2048]
  const float* w_o = (const float*)d_in[2];    // [2048,2048]
  float* y = (float*)d_out;                    // [2,2048,2048] fp32
  char* ws = (char*)d_ws;

  const size_t SZ_X = 16777216;     // 4096*2048*2 B
  const size_t SZ_WQKV = 25165824;  // 6144*2048*2 B
  const size_t SZ_Q = 16777216;     // 32*2048*128*2 B

  __hip_bfloat16* xb = (__hip_bfloat16*)(ws);            // x bf16; later attn out
  __hip_bfloat16* wqkvb = (__hip_bfloat16*)(ws + SZ_X);  // w_qkv bf16; later w_o bf16
  __hip_bfloat16* Qr = (__hip_bfloat16*)(ws + SZ_X + SZ_WQKV);
  __hip_bfloat16* Kr = (__hip_bfloat16*)(ws + SZ_X + SZ_WQKV + SZ_Q);
  __hip_bfloat16* Vt = (__hip_bfloat16*)(ws + SZ_X + SZ_WQKV + 2 * SZ_Q);

  cvt_kernel<<<dim3(8192), dim3(256), 0, stream>>>(x, xb, 8388608);
  cvt_kernel<<<dim3(12288), dim3(256), 0, stream>>>(w_qkv, wqkvb, 12582912);
  gemm_qkv_fused<<<dim3(32, 48), dim3(256), 0, stream>>>(xb, wqkvb, Qr, Kr, Vt);
  attn_swa<<<dim3(32, 32), dim3(256), 0, stream>>>(Qr, Kr, Vt, xb /*attn_out*/);
  cvt_kernel<<<dim3(4096), dim3(256), 0, stream>>>(w_o, wqkvb, 4194304);
  gemm_bt<<<dim3(32, 16), dim3(256), 0, stream>>>(xb, wqkvb, (void*)y, 4096, 2048, 2048, 1);
}

// Round 3
// 399.260 us; speedup vs baseline: 1.1161x; 1.0358x over previous
//
#include <hip/hip_runtime.h>
#include <hip/hip_bf16.h>
#include <cstdint>

typedef __bf16 bf16x8 __attribute__((ext_vector_type(8)));
typedef float floatx4 __attribute__((ext_vector_type(4)));

__device__ __forceinline__ void gl2lds16(const void* g, void* l) {
  __builtin_amdgcn_global_load_lds(
      (const __attribute__((address_space(1))) unsigned int*)g,
      (__attribute__((address_space(3))) unsigned int*)(uintptr_t)l,
      16, 0, 0);
}

// ---------------- fp32 -> bf16 convert ----------------
__global__ __launch_bounds__(256)
void cvt_kernel(const float* __restrict__ in, __hip_bfloat16* __restrict__ out, int n) {
  int i = (blockIdx.x * 256 + threadIdx.x) * 4;
  if (i >= n) return;
  const float4 v = *(const float4*)(in + i);
  out[i + 0] = __float2bfloat16(v.x);
  out[i + 1] = __float2bfloat16(v.y);
  out[i + 2] = __float2bfloat16(v.z);
  out[i + 3] = __float2bfloat16(v.w);
}

// ---------------- plain bf16 GEMM (O-proj): C[M][Nc] = A[M][K] * B[Nc][K]^T ----
__global__ __launch_bounds__(256)
void gemm_bt(const __hip_bfloat16* __restrict__ A, const __hip_bfloat16* __restrict__ Bm,
             void* __restrict__ Cp, int M, int Nc, int K, int c_fp32)
{
  __shared__ __hip_bfloat16 As[128 * 32];
  __shared__ __hip_bfloat16 Bs[128 * 32];
  const int tid = threadIdx.x;
  const int lane = tid & 63, wave = tid >> 6;
  const int wm = (wave & 1) * 64, wn = (wave >> 1) * 64;
  const int m0 = blockIdx.x * 128, n0 = blockIdx.y * 128;
  const int lrow = lane & 15, lk = (lane >> 4) * 8;
  floatx4 acc[4][4] = {};
  const int c0 = tid, c1 = tid + 256;
  const int r0 = c0 >> 2, o0 = (c0 & 3) * 8;
  const int r1 = c1 >> 2, o1 = (c1 & 3) * 8;
  for (int kt = 0; kt < K; kt += 32) {
    __syncthreads();
    gl2lds16(A + (size_t)(m0 + r0) * K + kt + o0, &As[c0 * 8]);
    gl2lds16(A + (size_t)(m0 + r1) * K + kt + o1, &As[c1 * 8]);
    gl2lds16(Bm + (size_t)(n0 + r0) * K + kt + o0, &Bs[c0 * 8]);
    gl2lds16(Bm + (size_t)(n0 + r1) * K + kt + o1, &Bs[c1 * 8]);
    __syncthreads();
    bf16x8 af[4], bfr[4];
#pragma unroll
    for (int t = 0; t < 4; t++) af[t] = *(const bf16x8*)&As[(wm + t * 16 + lrow) * 32 + lk];
#pragma unroll
    for (int t = 0; t < 4; t++) bfr[t] = *(const bf16x8*)&Bs[(wn + t * 16 + lrow) * 32 + lk];
#pragma unroll
    for (int mt = 0; mt < 4; mt++)
#pragma unroll
      for (int nt = 0; nt < 4; nt++)
        acc[mt][nt] = __builtin_amdgcn_mfma_f32_16x16x32_bf16(af[mt], bfr[nt], acc[mt][nt], 0, 0, 0);
  }
  const int lq4 = (lane >> 4) * 4;
#pragma unroll
  for (int mt = 0; mt < 4; mt++)
#pragma unroll
    for (int nt = 0; nt < 4; nt++)
#pragma unroll
      for (int r = 0; r < 4; r++) {
        const int m = m0 + wm + mt * 16 + lq4 + r;
        const int n = n0 + wn + nt * 16 + lrow;
        const float v = acc[mt][nt][r];
        if (c_fp32) ((float*)Cp)[(size_t)m * Nc + n] = v;
        else ((__hip_bfloat16*)Cp)[(size_t)m * Nc + n] = __float2bfloat16(v);
      }
}

// ---------------- QKV GEMM with fused RoPE + relayout epilogue ----------------
__global__ __launch_bounds__(256)
void gemm_qkv_fused(const __hip_bfloat16* __restrict__ A,
                    const __hip_bfloat16* __restrict__ W,
                    __hip_bfloat16* __restrict__ Qr,
                    __hip_bfloat16* __restrict__ Kr,
                    __hip_bfloat16* __restrict__ Vt)
{
  __shared__ alignas(16) char smem[16640];     // union: As+Bs (16384) | Cs 64x130 bf16 (16640)
  __shared__ float invf[64];
  __hip_bfloat16* As = (__hip_bfloat16*)smem;
  __hip_bfloat16* Bs = As + 128 * 32;
  __hip_bfloat16* Cs = (__hip_bfloat16*)smem;  // [64][130]
  const int tid = threadIdx.x;
  if (tid < 64) invf[tid] = __expf(-(float)tid * 0.14391156831212787f);  // 10000^(-t/64)
  const int lane = tid & 63, wave = tid >> 6;
  const int wm = (wave & 1) * 64, wn = (wave >> 1) * 64;
  const int m0 = blockIdx.x * 128, n0 = blockIdx.y * 128;
  const int K = 2048;
  const int lrow = lane & 15, lk = (lane >> 4) * 8;
  floatx4 acc[4][4] = {};
  const int c0 = tid, c1 = tid + 256;
  const int r0 = c0 >> 2, o0 = (c0 & 3) * 8;
  const int r1 = c1 >> 2, o1 = (c1 & 3) * 8;
  for (int kt = 0; kt < K; kt += 32) {
    __syncthreads();
    gl2lds16(A + (size_t)(m0 + r0) * K + kt + o0, &As[c0 * 8]);
    gl2lds16(A + (size_t)(m0 + r1) * K + kt + o1, &As[c1 * 8]);
    gl2lds16(W + (size_t)(n0 + r0) * K + kt + o0, &Bs[c0 * 8]);
    gl2lds16(W + (size_t)(n0 + r1) * K + kt + o1, &Bs[c1 * 8]);
    __syncthreads();
    bf16x8 af[4], bfr[4];
#pragma unroll
    for (int t = 0; t < 4; t++) af[t] = *(const bf16x8*)&As[(wm + t * 16 + lrow) * 32 + lk];
#pragma unroll
    for (int t = 0; t < 4; t++) bfr[t] = *(const bf16x8*)&Bs[(wn + t * 16 + lrow) * 32 + lk];
#pragma unroll
    for (int mt = 0; mt < 4; mt++)
#pragma unroll
      for (int nt = 0; nt < 4; nt++)
        acc[mt][nt] = __builtin_amdgcn_mfma_f32_16x16x32_bf16(af[mt], bfr[nt], acc[mt][nt], 0, 0, 0);
  }
  const int lq4 = (lane >> 4) * 4;
  const int seg = n0 >> 11;            // 0=Q 1=K 2=V
  const int h = (n0 & 2047) >> 7;
  const int b = m0 >> 11;
  const int bh = b * 16 + h;
  const int seq0 = m0 & 2047;
  const float qscale = (seg == 0) ? 0.08838834764831845f : 1.0f;
  for (int pass = 0; pass < 2; ++pass) {
    __syncthreads();
    if ((wave & 1) == pass) {
#pragma unroll
      for (int mt = 0; mt < 4; mt++)
#pragma unroll
        for (int nt = 0; nt < 4; nt++)
#pragma unroll
          for (int r = 0; r < 4; r++)
            Cs[(mt * 16 + lq4 + r) * 130 + wn + nt * 16 + lrow] =
                __float2bfloat16(acc[mt][nt][r]);
    }
    __syncthreads();
    if (seg < 2) {
      __hip_bfloat16* Out = seg ? Kr : Qr;
#pragma unroll
      for (int p = 0; p < 2; ++p) {
        const int row = (tid >> 3) + p * 32;
        const int oct = (tid & 7) * 8;
        const int m = m0 + pass * 64 + row;
        const float pos = (float)(m & 2047);
        alignas(16) __hip_bfloat16 lo[8], hi[8];
#pragma unroll
        for (int k2 = 0; k2 < 8; k2++) {
          const float ang = pos * invf[oct + k2];
          float sn, cs2;
          __sincosf(ang, &sn, &cs2);
          const float a  = __bfloat162float(Cs[row * 130 + oct + k2]);
          const float bb = __bfloat162float(Cs[row * 130 + oct + k2 + 64]);
          lo[k2] = __float2bfloat16((a * cs2 - bb * sn) * qscale);
          hi[k2] = __float2bfloat16((bb * cs2 + a * sn) * qscale);
        }
        const size_t ob = ((size_t)bh * 2048 + (size_t)(m & 2047)) * 128;
        *(bf16x8*)&Out[ob + oct]      = *(const bf16x8*)lo;
        *(bf16x8*)&Out[ob + oct + 64] = *(const bf16x8*)hi;
      }
    } else {
#pragma unroll
      for (int p = 0; p < 4; ++p) {
        const int d = (tid >> 3) + p * 32;
        const int s8 = (tid & 7) * 8;
        alignas(16) __hip_bfloat16 tmp[8];
#pragma unroll
        for (int k2 = 0; k2 < 8; k2++) tmp[k2] = Cs[(s8 + k2) * 130 + d];
        const size_t ob = ((size_t)bh * 128 + d) * 2048 + seq0 + pass * 64 + s8;
        *(bf16x8*)&Vt[ob] = *(const bf16x8*)tmp;
      }
    }
  }
}

// ---------------- sliding-window flash attention, S^T layout ----------------
// 128 q-rows/block, 8 waves; each wave owns 16 q-rows; lane&15 = q-row (scalar m/l).
// S^T = K*Q^T via operand swap; P^T packs as ds_write_b64; O^T = V^T * P^T.
__global__ __launch_bounds__(512)
void attn_swa(const __hip_bfloat16* __restrict__ Qr, const __hip_bfloat16* __restrict__ Kr,
              const __hip_bfloat16* __restrict__ Vt, __hip_bfloat16* __restrict__ Out)
{
  __shared__ __hip_bfloat16 Ks[64 * 128];    // K tile [j][d]; also stages Q rows 0..63
  __shared__ __hip_bfloat16 Vs[128 * 64];    // V^T tile [d][j]; also stages Q rows 64..127
  __shared__ __hip_bfloat16 Pb[8][16 * 72];  // per-wave P[i][j], padded stride 72
  const int qt = blockIdx.x, bh = blockIdx.y;
  const int tid = threadIdx.x, lane = tid & 63, wave = tid >> 6;
  const int lrow = lane & 15, lk = (lane >> 4) * 8, lq4 = (lane >> 4) * 4;
  const int i0 = qt * 128;
  const float NEG_INF = -__builtin_inff();
  const __hip_bfloat16* Qh = Qr + (size_t)bh * 2048 * 128;
  const __hip_bfloat16* Kh = Kr + (size_t)bh * 2048 * 128;
  const __hip_bfloat16* Vh = Vt + (size_t)bh * 128 * 2048;

  // --- stage Q (128x128) through Ks|Vs, pull this wave's frags to registers ---
#pragma unroll
  for (int it = 0; it < 4; it++) {
    const int c = it * 512 + tid;             // covers 2048 slots of 8 elems
    __hip_bfloat16* dst = (c < 1024) ? &Ks[c * 8] : &Vs[(c - 1024) * 8];
    gl2lds16(Qh + (size_t)(i0 + (c >> 4)) * 128 + (c & 15) * 8, dst);
  }
  __syncthreads();
  bf16x8 qf[4];
  {
    const __hip_bfloat16* qbuf = (wave < 4) ? Ks : Vs;
    const int qrow = (wave & 3) * 16 + lrow;
#pragma unroll
    for (int ks = 0; ks < 4; ks++)
      qf[ks] = *(const bf16x8*)&qbuf[qrow * 128 + ks * 32 + lk];
  }

  floatx4 accO[8] = {};
  float m_i = NEG_INF, l_i = 0.f;
  const int iw = i0 + wave * 16 + lrow;       // this lane's q row
  const int imin = i0 + wave * 16;
  const int lo = i0 - 511;
  const int jt_lo = (lo > 0 ? lo : 0) >> 6;
  const int jt_hi = (i0 + 127) >> 6;

  for (int jt = jt_lo; jt <= jt_hi; jt++) {
    const int j0 = jt * 64;
    __syncthreads();   // prior-iter LDS reads (and initial Q frag reads) done
#pragma unroll
    for (int it = 0; it < 2; it++) {
      const int c = it * 512 + tid;
      gl2lds16(Kh + (size_t)(j0 + (c >> 4)) * 128 + (c & 15) * 8, &Ks[c * 8]);
      gl2lds16(Vh + (size_t)(c >> 3) * 2048 + j0 + (c & 7) * 8, &Vs[c * 8]);
    }
    __syncthreads();
    // S^T[j][i] = sum_d K[j][d] Q[i][d]  (A=K-frag, B=Q-frag; Q pre-scaled)
    floatx4 s[4] = {};
#pragma unroll
    for (int nt = 0; nt < 4; nt++)
#pragma unroll
      for (int ks = 0; ks < 4; ks++) {
        const bf16x8 kf = *(const bf16x8*)&Ks[(nt * 16 + lrow) * 128 + ks * 32 + lk];
        s[nt] = __builtin_amdgcn_mfma_f32_16x16x32_bf16(kf, qf[ks], s[nt], 0, 0, 0);
      }
    // lane holds: i = iw (fixed), j = j0 + nt*16 + lq4 + r
    const bool full = (j0 + 63 <= imin) && (j0 >= imin + 15 - 511);
    float rmax = NEG_INF;
    if (full) {
#pragma unroll
      for (int nt = 0; nt < 4; nt++)
#pragma unroll
        for (int r = 0; r < 4; r++) rmax = fmaxf(rmax, s[nt][r]);
    } else {
#pragma unroll
      for (int nt = 0; nt < 4; nt++) {
#pragma unroll
        for (int r = 0; r < 4; r++) {
          const int j = j0 + nt * 16 + lq4 + r;
          const float sv = ((j <= iw) && (j > iw - 512)) ? s[nt][r] : NEG_INF;
          s[nt][r] = sv;
          rmax = fmaxf(rmax, sv);
        }
      }
    }
    rmax = fmaxf(rmax, __shfl_xor(rmax, 16));
    rmax = fmaxf(rmax, __shfl_xor(rmax, 32));
    const float mnew = fmaxf(m_i, rmax);
    const float alpha = __expf(fminf(m_i - mnew, 0.f));  // guards (-inf)-(-inf)
    m_i = mnew;
    float rs = 0.f;
    if (full) {
#pragma unroll
      for (int nt = 0; nt < 4; nt++)
#pragma unroll
        for (int r = 0; r < 4; r++) {
          const float p = __expf(s[nt][r] - mnew);
          s[nt][r] = p;
          rs += p;
        }
    } else {
#pragma unroll
      for (int nt = 0; nt < 4; nt++)
#pragma unroll
        for (int r = 0; r < 4; r++) {
          const float sv = s[nt][r];
          const float p = (sv == NEG_INF) ? 0.f : __expf(sv - mnew);
          s[nt][r] = p;
          rs += p;
        }
    }
    rs += __shfl_xor(rs, 16);
    rs += __shfl_xor(rs, 32);
    l_i = l_i * alpha + rs;
#pragma unroll
    for (int dt = 0; dt < 8; dt++) accO[dt] *= alpha;
    // P^T -> Pb[i][j] as packed b64 (4 consecutive j per write), wave-private
#pragma unroll
    for (int nt = 0; nt < 4; nt++) {
      alignas(8) __hip_bfloat16 p4[4];
#pragma unroll
      for (int r = 0; r < 4; r++) p4[r] = __float2bfloat16(s[nt][r]);
      *(uint64_t*)&Pb[wave][lrow * 72 + nt * 16 + lq4] = *(const uint64_t*)p4;
    }
    // O^T[d][i] += sum_j V^T[d][j] P[i][j]  (A=V^T-frag, B=P-frag)
    bf16x8 pf[2];
#pragma unroll
    for (int jf = 0; jf < 2; jf++)
      pf[jf] = *(const bf16x8*)&Pb[wave][lrow * 72 + jf * 32 + lk];
#pragma unroll
    for (int dt = 0; dt < 8; dt++)
#pragma unroll
      for (int jf = 0; jf < 2; jf++) {
        const bf16x8 vf = *(const bf16x8*)&Vs[(dt * 16 + lrow) * 64 + jf * 32 + lk];
        accO[dt] = __builtin_amdgcn_mfma_f32_16x16x32_bf16(vf, pf[jf], accO[dt], 0, 0, 0);
      }
  }
  // write: lane has O^T[d = dt*16+lq4+r][i = iw]; pack 4 consecutive d as 8B
  const int b = bh >> 4, h = bh & 15;
  const float inv_l = 1.0f / l_i;
  const size_t rowb = ((size_t)(b * 2048 + iw)) * 2048 + h * 128;
#pragma unroll
  for (int dt = 0; dt < 8; dt++) {
    alignas(8) __hip_bfloat16 o4[4];
#pragma unroll
    for (int r = 0; r < 4; r++) o4[r] = __float2bfloat16(accO[dt][r] * inv_l);
    *(uint64_t*)&Out[rowb + dt * 16 + lq4] = *(const uint64_t*)o4;
  }
}

// ---------------- launch ----------------
extern "C" void kernel_launch(void* const* d_in, const int* in_sizes, int n_in,
                              void* d_out, int out_size, void* d_ws, size_t ws_size,
                              hipStream_t stream)
{
  const float* x = (const float*)d_in[0];      // [2,2048,2048]
  const float* w_qkv = (const float*)d_in[1];  // [6144,2048]
  const float* w_o = (const float*)d_in[2];    // [2048,2048]
  float* y = (float*)d_out;                    // [2,2048,2048] fp32
  char* ws = (char*)d_ws;

  const size_t SZ_X = 16777216;     // 4096*2048*2 B
  const size_t SZ_WQKV = 25165824;  // 6144*2048*2 B
  const size_t SZ_Q = 16777216;     // 32*2048*128*2 B

  __hip_bfloat16* xb = (__hip_bfloat16*)(ws);            // x bf16; later attn out
  __hip_bfloat16* wqkvb = (__hip_bfloat16*)(ws + SZ_X);  // w_qkv bf16; later w_o bf16
  __hip_bfloat16* Qr = (__hip_bfloat16*)(ws + SZ_X + SZ_WQKV);
  __hip_bfloat16* Kr = (__hip_bfloat16*)(ws + SZ_X + SZ_WQKV + SZ_Q);
  __hip_bfloat16* Vt = (__hip_bfloat16*)(ws + SZ_X + SZ_WQKV + 2 * SZ_Q);

  cvt_kernel<<<dim3(8192), dim3(256), 0, stream>>>(x, xb, 8388608);
  cvt_kernel<<<dim3(12288), dim3(256), 0, stream>>>(w_qkv, wqkvb, 12582912);
  gemm_qkv_fused<<<dim3(32, 48), dim3(256), 0, stream>>>(xb, wqkvb, Qr, Kr, Vt);
  attn_swa<<<dim3(16, 32), dim3(512), 0, stream>>>(Qr, Kr, Vt, xb /*attn_out*/);
  cvt_kernel<<<dim3(4096), dim3(256), 0, stream>>>(w_o, wqkvb, 4194304);
  gemm_bt<<<dim3(32, 16), dim3(256), 0, stream>>>(xb, wqkvb, (void*)y, 4096, 2048, 2048, 1);
}